// Round 7
// baseline (376.068 us; speedup 1.0000x reference)
//
#include <hip/hip_runtime.h>

typedef __bf16 bf16x8 __attribute__((ext_vector_type(8)));
typedef float f32x16 __attribute__((ext_vector_type(16)));
typedef unsigned short us8 __attribute__((ext_vector_type(8)));

#define AS1 __attribute__((address_space(1)))
#define AS3 __attribute__((address_space(3)))

__device__ __forceinline__ unsigned short f2bf(float x) {
  unsigned int u = __float_as_uint(x);
  u += 0x7fffu + ((u >> 16) & 1u);   // RNE
  return (unsigned short)(u >> 16);
}
__device__ __forceinline__ float bf2f(unsigned short u) {
  return __uint_as_float(((unsigned int)u) << 16);
}
__device__ __forceinline__ void async_copy16(const void* g, void* l) {
  __builtin_amdgcn_global_load_lds((AS1 void*)(g), (AS3 void*)(l), 16, 0, 0);
}

// ------------- prep: all f32->bf16 conversions + P zeroing, one launch -------------
__global__ void __launch_bounds__(256) k_prep(const float* __restrict__ x,
                                              const float* __restrict__ W1,
                                              const float* __restrict__ W2,
                                              const float* __restrict__ W3,
                                              unsigned short* __restrict__ Xb,
                                              unsigned short* __restrict__ W1b,
                                              unsigned short* __restrict__ W2b,
                                              unsigned short* __restrict__ W3b,
                                              float* __restrict__ P) {
  const long n1 = 2097152, n2 = 524288, n3 = 1048576, n4 = 524288;
  long i = (long)blockIdx.x * 256 + threadIdx.x;   // float4 group index
  const float* s = nullptr;
  unsigned short* d = nullptr;
  long j = i;
  if (i < n1)                { s = x;  d = Xb; }
  else if ((j -= n1) < n2)   { s = W1; d = W1b; }
  else if ((j -= n2) < n3)   { s = W2; d = W2b; }
  else if ((j -= n3) < n4) {
    // W3: [1000,2048] -> padded [1024,2048], zero rows >= 1000
    ushort4 o;
    if ((j >> 9) < 1000) {
      float4 v = ((const float4*)W3)[j];
      o.x = f2bf(v.x); o.y = f2bf(v.y); o.z = f2bf(v.z); o.w = f2bf(v.w);
    } else { o.x = 0; o.y = 0; o.z = 0; o.w = 0; }
    ((ushort4*)W3b)[j] = o;
    return;
  } else {
    j -= n4;                                        // 0..2047 -> zero P (2 buffers)
    ((float4*)P)[j] = (float4){0.f, 0.f, 0.f, 0.f};
    return;
  }
  float4 v = ((const float4*)s)[j];
  ushort4 o;
  o.x = f2bf(v.x); o.y = f2bf(v.y); o.z = f2bf(v.z); o.w = f2bf(v.w);
  ((ushort4*)d)[j] = o;
}

// ---------------- GEMM: C[M,N] = A[M,K] * B[N,K]^T, bf16 in -----------------------
// 128(M)x256(N) tile, 4 waves, wave tile 64x128.
// A-OPERAND DIRECT FROM GLOBAL: mfma 32x32x16 A-layout (lane l: m=l&31,
// k=(l>>5)*8+j) is one aligned 16B segment/lane -> global_load_dwordx4 into VGPRs,
// no LDS round-trip for A (removes 1/3 of LDS b128 reads + A staging writes +
// 4 of 12 DMA copies from the barrier drain). A-stripe reused by 8 n-blocks per
// XCD -> L2 hits. Only B is staged via global_load_lds w=16 (XOR chunk swizzle).
// BK=64, 32 KB LDS, 2 blocks/CU.
// XCD swizzle: flat%8 = XCD; each XCD owns a contiguous m-stripe (A L2 locality).
// blockIdx.z = K-split slice: A/B advance z*K, C goes to Cout (z=0) / Cout2 (z=1).
// STATS: per-column sum/sumsq of C atomically into P[0..2047]/P[2048..4095].
template <bool OUTBF16, bool STATS>
__global__ void __launch_bounds__(256, 2) k_gemm(const unsigned short* __restrict__ A,
                                                 const unsigned short* __restrict__ B,
                                                 void* __restrict__ Cout,
                                                 void* __restrict__ Cout2, int K,
                                                 int lda, int ldb, int ldc,
                                                 float* __restrict__ P) {
  __shared__ __align__(16) unsigned short lB[256 * 64];   // 32 KB
  const int tid = threadIdx.x;
  const int wave = tid >> 6;
  const int lane = tid & 63;

  // XCD-aware remap of (blockIdx.x, blockIdx.y) -> (nblk, mblk)
  const int f = blockIdx.x + gridDim.x * blockIdx.y;
  const int xcd = f & 7;
  const int fi = f >> 3;
  const int nblk = fi % gridDim.x;
  const int mblk = fi / gridDim.x + (gridDim.y >> 3) * xcd;
  const long m0 = (long)mblk * 128;
  const long n0 = (long)nblk * 256;
  const long koff = (long)blockIdx.z * K;

  // B staging: wave covers rows [wave*64, +64), 8 rounds of 8 rows.
  // LDS slot (row,pos) holds global chunk (pos ^ (row&7)); lane l -> row l>>3, pos l&7.
  const int rsub = lane >> 3;                     // 0..7
  const int qg = ((lane & 7) ^ rsub) * 8;         // swizzled global chunk (halves)
  const unsigned short* gB = B + (n0 + wave * 64 + rsub) * (long)ldb + koff + qg;
  unsigned short* lBw = lB + (wave * 64) * 64;

  const int wr = (wave >> 1) * 64;                // wave row offset in tile (0,64)
  const int wc = (wave & 1) * 128;                // wave col offset (0,128)
  const int l31 = lane & 31;
  const int khalf = lane >> 5;                    // 0..1
  const int r7 = l31 & 7;                         // fragment row & 7 (swizzle key)

  // A-fragment base: lane reads A[m0+wr+i*32+l31][koff+k0+ks*16+khalf*8 ..+7]
  const unsigned short* gAf = A + (m0 + wr + l31) * (long)lda + koff + khalf * 8;

  f32x16 acc[2][4];
#pragma unroll
  for (int i = 0; i < 2; ++i)
#pragma unroll
    for (int j = 0; j < 4; ++j) acc[i][j] = (f32x16)(0.f);

  for (int k0 = 0; k0 < K; k0 += 64) {
    // A-fragments for this K-slab: 8x dwordx4 from global (L2-resident stripe),
    // issued before B staging so they fly during the barrier drain.
    bf16x8 af[2][4];
#pragma unroll
    for (int i = 0; i < 2; ++i)
#pragma unroll
      for (int ks = 0; ks < 4; ++ks)
        af[i][ks] = *(const bf16x8*)(gAf + (long)i * 32 * lda + k0 + ks * 16);

#pragma unroll
    for (int r = 0; r < 8; ++r)
      async_copy16(gB + (long)(r * 8) * ldb + k0, lBw + r * 8 * 64);
    __syncthreads();

#pragma unroll
    for (int ks = 0; ks < 4; ++ks) {             // K-step of 16
      const int off = ((ks * 2 + khalf) ^ r7) * 8;
      bf16x8 bfr[4];
#pragma unroll
      for (int j = 0; j < 4; ++j)
        bfr[j] = *(const bf16x8*)&lB[(wc + j * 32 + l31) * 64 + off];
#pragma unroll
      for (int i = 0; i < 2; ++i)
#pragma unroll
        for (int j = 0; j < 4; ++j)
          acc[i][j] = __builtin_amdgcn_mfma_f32_32x32x16_bf16(af[i][ks], bfr[j], acc[i][j], 0, 0, 0);
    }
    __syncthreads();
  }

  // C/D layout: col = lane&31, row = (reg&3) + 8*(reg>>2) + 4*(lane>>5)
  const int rbase = 4 * khalf;
  if (OUTBF16) {
    unsigned short* C = (unsigned short*)Cout;
#pragma unroll
    for (int i = 0; i < 2; ++i)
#pragma unroll
      for (int j = 0; j < 4; ++j) {
        long col = n0 + wc + j * 32 + l31;
#pragma unroll
        for (int reg = 0; reg < 16; ++reg) {
          long row = m0 + wr + i * 32 + (reg & 3) + 8 * (reg >> 2) + rbase;
          C[row * (long)ldc + col] = f2bf(acc[i][j][reg]);
        }
      }
  } else {
    float* C = (float*)(blockIdx.z ? Cout2 : Cout);
#pragma unroll
    for (int i = 0; i < 2; ++i)
#pragma unroll
      for (int j = 0; j < 4; ++j) {
        long col = n0 + wc + j * 32 + l31;
#pragma unroll
        for (int reg = 0; reg < 16; ++reg) {
          long row = m0 + wr + i * 32 + (reg & 3) + 8 * (reg >> 2) + rbase;
          C[row * (long)ldc + col] = acc[i][j][reg];
        }
      }
  }

  if (STATS) {
    float* sred = (float*)lB;    // reuse LDS (post final barrier): 512 floats
    sred[tid] = 0.f;
    sred[256 + tid] = 0.f;       // sum[0..255], sumsq[256..511]
    __syncthreads();
#pragma unroll
    for (int j = 0; j < 4; ++j) {
      float s = 0.f, s2 = 0.f;
#pragma unroll
      for (int i = 0; i < 2; ++i)
#pragma unroll
        for (int reg = 0; reg < 16; ++reg) {
          float v = acc[i][j][reg];
          s += v;
          s2 = fmaf(v, v, s2);
        }
      int cl = wc + j * 32 + l31;      // 0..255
      atomicAdd(&sred[cl], s);
      atomicAdd(&sred[256 + cl], s2);
    }
    __syncthreads();
    atomicAdd(&P[n0 + tid], sred[tid]);
    atomicAdd(&P[2048 + n0 + tid], sred[256 + tid]);
  }
}

// ------- fused BN-finalize + BN-apply + relu + row-norm + hyperbolic factor -------
// One wave per row. Each lane handles cols (lane+64c)*8..+7, c=0..3; scale/shift
// computed per-lane from P/g/be (L2-hit redundant reads).
template <bool STAGE2>
__global__ void __launch_bounds__(256) k_fuse(const unsigned short* __restrict__ Zb,
                                              const float* __restrict__ P,
                                              const float* __restrict__ g,
                                              const float* __restrict__ be,
                                              unsigned short* __restrict__ Ab) {
  const int t = threadIdx.x, wave = t >> 6, lane = t & 63;
  const long row = (long)blockIdx.x * 4 + wave;

  float sc[32], sh[32];
#pragma unroll
  for (int c = 0; c < 4; ++c) {
    int b4 = (lane + 64 * c) * 2;                 // float4 index of col base
    float4 s0 = ((const float4*)P)[b4],       s1 = ((const float4*)P)[b4 + 1];
    float4 q0 = ((const float4*)P)[512 + b4], q1 = ((const float4*)P)[512 + b4 + 1];
    float4 g0 = ((const float4*)g)[b4],       g1 = ((const float4*)g)[b4 + 1];
    float4 e0 = ((const float4*)be)[b4],      e1 = ((const float4*)be)[b4 + 1];
    float sm[8] = {s0.x, s0.y, s0.z, s0.w, s1.x, s1.y, s1.z, s1.w};
    float sq[8] = {q0.x, q0.y, q0.z, q0.w, q1.x, q1.y, q1.z, q1.w};
    float gg[8] = {g0.x, g0.y, g0.z, g0.w, g1.x, g1.y, g1.z, g1.w};
    float bb[8] = {e0.x, e0.y, e0.z, e0.w, e1.x, e1.y, e1.z, e1.w};
#pragma unroll
    for (int j = 0; j < 8; ++j) {
      float mean = sm[j] * (1.f / 8192.f);
      float var = sq[j] * (1.f / 8192.f) - mean * mean;
      float a = gg[j] * rsqrtf(var + 1e-5f);
      sc[c * 8 + j] = a;
      sh[c * 8 + j] = bb[j] - mean * a;
    }
  }

  const us8* zr = (const us8*)(Zb + row * 2048);
  float v[32];
  float ss = 0.f;
#pragma unroll
  for (int c = 0; c < 4; ++c) {
    us8 z8 = zr[lane + 64 * c];
#pragma unroll
    for (int j = 0; j < 8; ++j) {
      float xv = fmaxf(fmaf(bf2f(z8[j]), sc[c * 8 + j], sh[c * 8 + j]), 0.f);
      v[c * 8 + j] = xv;
      ss = fmaf(xv, xv, ss);
    }
  }
#pragma unroll
  for (int o = 32; o > 0; o >>= 1) ss += __shfl_xor(ss, o, 64);
  float n2 = ss;

  const float rsc = 0.31622776601683794f;  // sqrt(0.1)
  float fac;
  if (STAGE2) {
    float nn = sqrtf(n2);
    float vn = fmaxf(nn, 1e-8f);
    float tt = rsc * vn;
    float scl = tanhf(tt) / tt;
    float hn = scl * nn;
    float cn = fminf(fmaxf(hn, 1e-8f), 1.0f);
    float z = rsc * cn;
    fac = scl * (atanhf(z) / z);
  } else {
    fac = 0.f;
    if (n2 > 0.f) {
      float n = sqrtf(n2);
      float th = tanhf(rsc * n);
      float s = 0.9f * th / (rsc * n);
      float dn = fmaxf(s * n, 1e-8f);
      float z = rsc * dn;
      fac = -(atanhf(z) / z) * s;
    }
  }
  us8* dr = (us8*)(Ab + row * 2048);
#pragma unroll
  for (int c = 0; c < 4; ++c) {
    us8 o8;
#pragma unroll
    for (int j = 0; j < 8; ++j) o8[j] = f2bf(v[c * 8 + j] * fac);
    dr[lane + 64 * c] = o8;
  }
}

// -------- log_softmax over 1000 cols; one wave per row; sums split-K partials -----
__global__ void __launch_bounds__(256) k_lsm(const float* __restrict__ Za,
                                             const float* __restrict__ Zb2,
                                             const float* __restrict__ b3,
                                             float* __restrict__ out) {
  const int t = threadIdx.x, wave = t >> 6, lane = t & 63;
  const long row = (long)blockIdx.x * 4 + wave;
  const float* za = Za + row * 1024;
  const float* zb = Zb2 + row * 1024;
  float v[16];
  float mx = -3.4e38f;
#pragma unroll
  for (int c = 0; c < 16; ++c) {
    int col = lane + 64 * c;
    if (col < 1000) {
      v[c] = za[col] + zb[col] + b3[col];
      mx = fmaxf(mx, v[c]);
    } else v[c] = -3.4e38f;
  }
#pragma unroll
  for (int o = 32; o > 0; o >>= 1) mx = fmaxf(mx, __shfl_xor(mx, o, 64));

  float se = 0.f;
#pragma unroll
  for (int c = 0; c < 16; ++c) {
    int col = lane + 64 * c;
    if (col < 1000) se += expf(v[c] - mx);
  }
#pragma unroll
  for (int o = 32; o > 0; o >>= 1) se += __shfl_xor(se, o, 64);
  float ls = logf(se);

  float* orow = out + row * 1000;
#pragma unroll
  for (int c = 0; c < 16; ++c) {
    int col = lane + 64 * c;
    if (col < 1000) orow[col] = v[c] - mx - ls;
  }
}

extern "C" void kernel_launch(void* const* d_in, const int* in_sizes, int n_in,
                              void* d_out, int out_size, void* d_ws, size_t ws_size,
                              hipStream_t stream) {
  (void)in_sizes; (void)n_in; (void)out_size; (void)ws_size;
  const float* x   = (const float*)d_in[0];
  const float* W1  = (const float*)d_in[1];
  // d_in[2] = b1: exactly cancelled by BN (mean absorbs it)
  const float* g1  = (const float*)d_in[3];
  const float* be1 = (const float*)d_in[4];
  const float* W2  = (const float*)d_in[5];
  // d_in[6] = b2: cancelled by BN
  const float* g2  = (const float*)d_in[7];
  const float* be2 = (const float*)d_in[8];
  const float* W3  = (const float*)d_in[9];
  const float* b3  = (const float*)d_in[10];
  float* out = (float*)d_out;

  char* ws = (char*)d_ws;
  size_t off = 0;
  auto alloc = [&](size_t bytes) {
    void* p = ws + off;
    off += (bytes + 255) & ~(size_t)255;
    return p;
  };
  unsigned short* Xb  = (unsigned short*)alloc((size_t)8192 * 1024 * 2);
  unsigned short* W1b = (unsigned short*)alloc((size_t)2048 * 1024 * 2);
  unsigned short* W2b = (unsigned short*)alloc((size_t)2048 * 2048 * 2);
  unsigned short* W3b = (unsigned short*)alloc((size_t)1024 * 2048 * 2);
  unsigned short* Zb  = (unsigned short*)alloc((size_t)8192 * 2048 * 2);
  unsigned short* Ab  = (unsigned short*)alloc((size_t)8192 * 2048 * 2);
  float* Z3a          = (float*)alloc((size_t)8192 * 1024 * 4);
  float* P            = (float*)alloc((size_t)2 * 4096 * 4);   // P1 | P2, zeroed by k_prep
  float* P2 = P + 4096;
  // split-K slice-1 output aliases Zb (dead after k_fuse<true>; 32 MiB exactly)
  float* Z3b = (float*)Zb;

  // conversions + P zeroing
  k_prep<<<16392, 256, 0, stream>>>(x, W1, W2, W3, Xb, W1b, W2b, W3b, P);

  // layer 1: GEMM (+BN stats) -> fused BN-finalize+hyperbolic
  k_gemm<true, true><<<dim3(8, 64, 1), 256, 0, stream>>>(Xb, W1b, Zb, Zb, 1024, 1024, 1024, 2048, P);
  k_fuse<false><<<2048, 256, 0, stream>>>(Zb, P, g1, be1, Ab);

  // layer 2
  k_gemm<true, true><<<dim3(8, 64, 1), 256, 0, stream>>>(Ab, W2b, Zb, Zb, 2048, 2048, 2048, 2048, P2);
  k_fuse<true><<<2048, 256, 0, stream>>>(Zb, P2, g2, be2, Ab);

  // layer 3: split-K=2 in ONE launch (blockIdx.z), partials summed in k_lsm
  k_gemm<false, false><<<dim3(4, 64, 2), 256, 0, stream>>>(Ab, W3b, Z3a, Z3b, 1024, 2048, 2048, 1024, nullptr);
  k_lsm<<<2048, 256, 0, stream>>>(Z3a, Z3b, b3, out);
}

// Round 8
// 321.546 us; speedup vs baseline: 1.1696x; 1.1696x over previous
//
#include <hip/hip_runtime.h>

typedef __bf16 bf16x8 __attribute__((ext_vector_type(8)));
typedef float f32x16 __attribute__((ext_vector_type(16)));
typedef unsigned short us8 __attribute__((ext_vector_type(8)));

#define AS1 __attribute__((address_space(1)))
#define AS3 __attribute__((address_space(3)))

__device__ __forceinline__ unsigned short f2bf(float x) {
  unsigned int u = __float_as_uint(x);
  u += 0x7fffu + ((u >> 16) & 1u);   // RNE
  return (unsigned short)(u >> 16);
}
__device__ __forceinline__ float bf2f(unsigned short u) {
  return __uint_as_float(((unsigned int)u) << 16);
}
__device__ __forceinline__ void async_copy16(const void* g, void* l) {
  __builtin_amdgcn_global_load_lds((AS1 void*)(g), (AS3 void*)(l), 16, 0, 0);
}

// ------------- prep: all f32->bf16 conversions + P zeroing, one launch -------------
__global__ void __launch_bounds__(256) k_prep(const float* __restrict__ x,
                                              const float* __restrict__ W1,
                                              const float* __restrict__ W2,
                                              const float* __restrict__ W3,
                                              unsigned short* __restrict__ Xb,
                                              unsigned short* __restrict__ W1b,
                                              unsigned short* __restrict__ W2b,
                                              unsigned short* __restrict__ W3b,
                                              float* __restrict__ P) {
  const long n1 = 2097152, n2 = 524288, n3 = 1048576, n4 = 524288;
  long i = (long)blockIdx.x * 256 + threadIdx.x;   // float4 group index
  const float* s = nullptr;
  unsigned short* d = nullptr;
  long j = i;
  if (i < n1)                { s = x;  d = Xb; }
  else if ((j -= n1) < n2)   { s = W1; d = W1b; }
  else if ((j -= n2) < n3)   { s = W2; d = W2b; }
  else if ((j -= n3) < n4) {
    // W3: [1000,2048] -> padded [1024,2048], zero rows >= 1000
    ushort4 o;
    if ((j >> 9) < 1000) {
      float4 v = ((const float4*)W3)[j];
      o.x = f2bf(v.x); o.y = f2bf(v.y); o.z = f2bf(v.z); o.w = f2bf(v.w);
    } else { o.x = 0; o.y = 0; o.z = 0; o.w = 0; }
    ((ushort4*)W3b)[j] = o;
    return;
  } else {
    j -= n4;                                        // 0..2047 -> zero P (2 buffers)
    ((float4*)P)[j] = (float4){0.f, 0.f, 0.f, 0.f};
    return;
  }
  float4 v = ((const float4*)s)[j];
  ushort4 o;
  o.x = f2bf(v.x); o.y = f2bf(v.y); o.z = f2bf(v.z); o.w = f2bf(v.w);
  ((ushort4*)d)[j] = o;
}

// ---------------- GEMM: C[M,N] = A[M,K] * B[N,K]^T, bf16 in -----------------------
// r6 structure (best measured: 86.5 us @ 8192x2048x2048): 128(M)x256(N) tile,
// 4 waves, wave tile 64x128 (af[2] x bfr[4] -> 8 MFMA per 6 ds_read_b128), BK=64,
// 32x32x16 MFMA, XOR chunk swizzle (conflict floor only), global_load_lds w=16 for
// BOTH operands. r7 lesson: A direct-from-global is lane-strided (4KB apart) ->
// 512 scattered reqs/iter, regressed 86.5->110; LDS staging is what coalesces.
// XCD swizzle: flat%8 = XCD; each XCD owns a contiguous m-stripe (A L2 locality).
// blockIdx.z selects Cout/Cout2 (split-K partials for GEMM3, bf16).
// STATS: per-column sum/sumsq of C atomically into P[0..2047]/P[2048..4095].
template <bool OUTBF16, bool STATS>
__global__ void __launch_bounds__(256, 2) k_gemm(const unsigned short* __restrict__ A,
                                                 const unsigned short* __restrict__ B,
                                                 void* __restrict__ Cout,
                                                 void* __restrict__ Cout2, int K,
                                                 int lda, int ldb, int ldc,
                                                 float* __restrict__ P) {
  __shared__ __align__(16) unsigned short lA[128 * 64];   // 16 KB
  __shared__ __align__(16) unsigned short lB[256 * 64];   // 32 KB
  const int tid = threadIdx.x;
  const int wave = tid >> 6;
  const int lane = tid & 63;

  // XCD-aware remap of (blockIdx.x, blockIdx.y) -> (nblk, mblk)
  const int f = blockIdx.x + gridDim.x * blockIdx.y;
  const int xcd = f & 7;
  const int fi = f >> 3;
  const int nblk = fi % gridDim.x;
  const int mblk = fi / gridDim.x + (gridDim.y >> 3) * xcd;
  const long m0 = (long)mblk * 128;
  const long n0 = (long)nblk * 256;
  const long koff = (long)blockIdx.z * K;

  // staging: A — wave covers rows [wave*32, +32), 4 rounds of 8; B — [wave*64, +64),
  // 8 rounds of 8. LDS slot (row,pos) holds global chunk (pos ^ (row&7)).
  const int rsub = lane >> 3;                     // 0..7
  const int qg = ((lane & 7) ^ rsub) * 8;         // swizzled global chunk (halves)
  const unsigned short* gA = A + (m0 + wave * 32 + rsub) * (long)lda + koff + qg;
  const unsigned short* gB = B + (n0 + wave * 64 + rsub) * (long)ldb + koff + qg;
  unsigned short* lAw = lA + (wave * 32) * 64;
  unsigned short* lBw = lB + (wave * 64) * 64;

  const int wr = (wave >> 1) * 64;                // wave row offset in tile (0,64)
  const int wc = (wave & 1) * 128;                // wave col offset (0,128)
  const int l31 = lane & 31;
  const int khalf = lane >> 5;                    // 0..1
  const int r7 = l31 & 7;                         // fragment row & 7 (swizzle key)

  f32x16 acc[2][4];
#pragma unroll
  for (int i = 0; i < 2; ++i)
#pragma unroll
    for (int j = 0; j < 4; ++j) acc[i][j] = (f32x16)(0.f);

  for (int k0 = 0; k0 < K; k0 += 64) {
#pragma unroll
    for (int r = 0; r < 4; ++r)
      async_copy16(gA + (long)(r * 8) * lda + k0, lAw + r * 8 * 64);
#pragma unroll
    for (int r = 0; r < 8; ++r)
      async_copy16(gB + (long)(r * 8) * ldb + k0, lBw + r * 8 * 64);
    __syncthreads();

#pragma unroll
    for (int ks = 0; ks < 4; ++ks) {             // K-step of 16
      const int off = ((ks * 2 + khalf) ^ r7) * 8;
      bf16x8 af[2], bfr[4];
#pragma unroll
      for (int i = 0; i < 2; ++i)
        af[i] = *(const bf16x8*)&lA[(wr + i * 32 + l31) * 64 + off];
#pragma unroll
      for (int j = 0; j < 4; ++j)
        bfr[j] = *(const bf16x8*)&lB[(wc + j * 32 + l31) * 64 + off];
#pragma unroll
      for (int i = 0; i < 2; ++i)
#pragma unroll
        for (int j = 0; j < 4; ++j)
          acc[i][j] = __builtin_amdgcn_mfma_f32_32x32x16_bf16(af[i], bfr[j], acc[i][j], 0, 0, 0);
    }
    __syncthreads();
  }

  // C/D layout: col = lane&31, row = (reg&3) + 8*(reg>>2) + 4*(lane>>5)
  const int rbase = 4 * khalf;
  if (OUTBF16) {
    unsigned short* C = (unsigned short*)(blockIdx.z ? Cout2 : Cout);
#pragma unroll
    for (int i = 0; i < 2; ++i)
#pragma unroll
      for (int j = 0; j < 4; ++j) {
        long col = n0 + wc + j * 32 + l31;
#pragma unroll
        for (int reg = 0; reg < 16; ++reg) {
          long row = m0 + wr + i * 32 + (reg & 3) + 8 * (reg >> 2) + rbase;
          C[row * (long)ldc + col] = f2bf(acc[i][j][reg]);
        }
      }
  } else {
    float* C = (float*)(blockIdx.z ? Cout2 : Cout);
#pragma unroll
    for (int i = 0; i < 2; ++i)
#pragma unroll
      for (int j = 0; j < 4; ++j) {
        long col = n0 + wc + j * 32 + l31;
#pragma unroll
        for (int reg = 0; reg < 16; ++reg) {
          long row = m0 + wr + i * 32 + (reg & 3) + 8 * (reg >> 2) + rbase;
          C[row * (long)ldc + col] = acc[i][j][reg];
        }
      }
  }

  if (STATS) {
    float* sred = (float*)lA;    // reuse LDS (post final barrier): 512 floats
    sred[tid] = 0.f;
    sred[256 + tid] = 0.f;       // sum[0..255], sumsq[256..511]
    __syncthreads();
#pragma unroll
    for (int j = 0; j < 4; ++j) {
      float s = 0.f, s2 = 0.f;
#pragma unroll
      for (int i = 0; i < 2; ++i)
#pragma unroll
        for (int reg = 0; reg < 16; ++reg) {
          float v = acc[i][j][reg];
          s += v;
          s2 = fmaf(v, v, s2);
        }
      int cl = wc + j * 32 + l31;      // 0..255
      atomicAdd(&sred[cl], s);
      atomicAdd(&sred[256 + cl], s2);
    }
    __syncthreads();
    atomicAdd(&P[n0 + tid], sred[tid]);
    atomicAdd(&P[2048 + n0 + tid], sred[256 + tid]);
  }
}

// ------- fused BN-finalize + BN-apply + relu + row-norm + hyperbolic factor -------
// One wave per row. Each lane handles cols (lane+64c)*8..+7, c=0..3; scale/shift
// computed per-lane from P/g/be (L2-hit redundant reads).
template <bool STAGE2>
__global__ void __launch_bounds__(256) k_fuse(const unsigned short* __restrict__ Zb,
                                              const float* __restrict__ P,
                                              const float* __restrict__ g,
                                              const float* __restrict__ be,
                                              unsigned short* __restrict__ Ab) {
  const int t = threadIdx.x, wave = t >> 6, lane = t & 63;
  const long row = (long)blockIdx.x * 4 + wave;

  float sc[32], sh[32];
#pragma unroll
  for (int c = 0; c < 4; ++c) {
    int b4 = (lane + 64 * c) * 2;                 // float4 index of col base
    float4 s0 = ((const float4*)P)[b4],       s1 = ((const float4*)P)[b4 + 1];
    float4 q0 = ((const float4*)P)[512 + b4], q1 = ((const float4*)P)[512 + b4 + 1];
    float4 g0 = ((const float4*)g)[b4],       g1 = ((const float4*)g)[b4 + 1];
    float4 e0 = ((const float4*)be)[b4],      e1 = ((const float4*)be)[b4 + 1];
    float sm[8] = {s0.x, s0.y, s0.z, s0.w, s1.x, s1.y, s1.z, s1.w};
    float sq[8] = {q0.x, q0.y, q0.z, q0.w, q1.x, q1.y, q1.z, q1.w};
    float gg[8] = {g0.x, g0.y, g0.z, g0.w, g1.x, g1.y, g1.z, g1.w};
    float bb[8] = {e0.x, e0.y, e0.z, e0.w, e1.x, e1.y, e1.z, e1.w};
#pragma unroll
    for (int j = 0; j < 8; ++j) {
      float mean = sm[j] * (1.f / 8192.f);
      float var = sq[j] * (1.f / 8192.f) - mean * mean;
      float a = gg[j] * rsqrtf(var + 1e-5f);
      sc[c * 8 + j] = a;
      sh[c * 8 + j] = bb[j] - mean * a;
    }
  }

  const us8* zr = (const us8*)(Zb + row * 2048);
  float v[32];
  float ss = 0.f;
#pragma unroll
  for (int c = 0; c < 4; ++c) {
    us8 z8 = zr[lane + 64 * c];
#pragma unroll
    for (int j = 0; j < 8; ++j) {
      float xv = fmaxf(fmaf(bf2f(z8[j]), sc[c * 8 + j], sh[c * 8 + j]), 0.f);
      v[c * 8 + j] = xv;
      ss = fmaf(xv, xv, ss);
    }
  }
#pragma unroll
  for (int o = 32; o > 0; o >>= 1) ss += __shfl_xor(ss, o, 64);
  float n2 = ss;

  const float rsc = 0.31622776601683794f;  // sqrt(0.1)
  float fac;
  if (STAGE2) {
    float nn = sqrtf(n2);
    float vn = fmaxf(nn, 1e-8f);
    float tt = rsc * vn;
    float scl = tanhf(tt) / tt;
    float hn = scl * nn;
    float cn = fminf(fmaxf(hn, 1e-8f), 1.0f);
    float z = rsc * cn;
    fac = scl * (atanhf(z) / z);
  } else {
    fac = 0.f;
    if (n2 > 0.f) {
      float n = sqrtf(n2);
      float th = tanhf(rsc * n);
      float s = 0.9f * th / (rsc * n);
      float dn = fmaxf(s * n, 1e-8f);
      float z = rsc * dn;
      fac = -(atanhf(z) / z) * s;
    }
  }
  us8* dr = (us8*)(Ab + row * 2048);
#pragma unroll
  for (int c = 0; c < 4; ++c) {
    us8 o8;
#pragma unroll
    for (int j = 0; j < 8; ++j) o8[j] = f2bf(v[c * 8 + j] * fac);
    dr[lane + 64 * c] = o8;
  }
}

// ---- log_softmax over 1000 cols; one wave per row; sums bf16 split-K partials ----
__global__ void __launch_bounds__(256) k_lsm(const unsigned short* __restrict__ Za,
                                             const unsigned short* __restrict__ Zb2,
                                             const float* __restrict__ b3,
                                             float* __restrict__ out) {
  const int t = threadIdx.x, wave = t >> 6, lane = t & 63;
  const long row = (long)blockIdx.x * 4 + wave;
  const unsigned short* za = Za + row * 1024;
  const unsigned short* zb = Zb2 + row * 1024;
  float v[16];
  float mx = -3.4e38f;
#pragma unroll
  for (int c = 0; c < 16; ++c) {
    int col = lane + 64 * c;
    if (col < 1000) {
      v[c] = bf2f(za[col]) + bf2f(zb[col]) + b3[col];
      mx = fmaxf(mx, v[c]);
    } else v[c] = -3.4e38f;
  }
#pragma unroll
  for (int o = 32; o > 0; o >>= 1) mx = fmaxf(mx, __shfl_xor(mx, o, 64));

  float se = 0.f;
#pragma unroll
  for (int c = 0; c < 16; ++c) {
    int col = lane + 64 * c;
    if (col < 1000) se += expf(v[c] - mx);
  }
#pragma unroll
  for (int o = 32; o > 0; o >>= 1) se += __shfl_xor(se, o, 64);
  float ls = logf(se);

  float* orow = out + row * 1000;
#pragma unroll
  for (int c = 0; c < 16; ++c) {
    int col = lane + 64 * c;
    if (col < 1000) orow[col] = v[c] - mx - ls;
  }
}

extern "C" void kernel_launch(void* const* d_in, const int* in_sizes, int n_in,
                              void* d_out, int out_size, void* d_ws, size_t ws_size,
                              hipStream_t stream) {
  (void)in_sizes; (void)n_in; (void)out_size; (void)ws_size;
  const float* x   = (const float*)d_in[0];
  const float* W1  = (const float*)d_in[1];
  // d_in[2] = b1: exactly cancelled by BN (mean absorbs it)
  const float* g1  = (const float*)d_in[3];
  const float* be1 = (const float*)d_in[4];
  const float* W2  = (const float*)d_in[5];
  // d_in[6] = b2: cancelled by BN
  const float* g2  = (const float*)d_in[7];
  const float* be2 = (const float*)d_in[8];
  const float* W3  = (const float*)d_in[9];
  const float* b3  = (const float*)d_in[10];
  float* out = (float*)d_out;

  char* ws = (char*)d_ws;
  size_t off = 0;
  auto alloc = [&](size_t bytes) {
    void* p = ws + off;
    off += (bytes + 255) & ~(size_t)255;
    return p;
  };
  unsigned short* Xb  = (unsigned short*)alloc((size_t)8192 * 1024 * 2);
  unsigned short* W1b = (unsigned short*)alloc((size_t)2048 * 1024 * 2);
  unsigned short* W2b = (unsigned short*)alloc((size_t)2048 * 2048 * 2);
  unsigned short* W3b = (unsigned short*)alloc((size_t)1024 * 2048 * 2);
  unsigned short* Zb  = (unsigned short*)alloc((size_t)8192 * 2048 * 2);
  unsigned short* Ab  = (unsigned short*)alloc((size_t)8192 * 2048 * 2);
  unsigned short* Z3a = (unsigned short*)alloc((size_t)8192 * 1024 * 2);
  float* P            = (float*)alloc((size_t)2 * 4096 * 4);   // P1 | P2, zeroed by k_prep
  float* P2 = P + 4096;
  // split-K slice-1 output aliases Zb (dead after k_fuse<true>; 32 MiB >= 16 MiB)
  unsigned short* Z3b = Zb;

  // conversions + P zeroing
  k_prep<<<16392, 256, 0, stream>>>(x, W1, W2, W3, Xb, W1b, W2b, W3b, P);

  // layer 1: GEMM (+BN stats) -> fused BN-finalize+hyperbolic
  k_gemm<true, true><<<dim3(8, 64, 1), 256, 0, stream>>>(Xb, W1b, Zb, Zb, 1024, 1024, 1024, 2048, P);
  k_fuse<false><<<2048, 256, 0, stream>>>(Zb, P, g1, be1, Ab);

  // layer 2
  k_gemm<true, true><<<dim3(8, 64, 1), 256, 0, stream>>>(Ab, W2b, Zb, Zb, 2048, 2048, 2048, 2048, P2);
  k_fuse<true><<<2048, 256, 0, stream>>>(Zb, P2, g2, be2, Ab);

  // layer 3: split-K=2 in ONE launch (blockIdx.z), bf16 partials summed in k_lsm
  k_gemm<true, false><<<dim3(4, 64, 2), 256, 0, stream>>>(Ab, W3b, Z3a, Z3b, 1024, 2048, 2048, 1024, nullptr);
  k_lsm<<<2048, 256, 0, stream>>>(Z3a, Z3b, b3, out);
}